// Round 1
// baseline (832.714 us; speedup 1.0000x reference)
//
#include <hip/hip_runtime.h>

// RoPE: q,k fp32 [B=4, S=4096, E=4096], H = E/128 = 32 heads, ROTARY_DIM=128.
// out[d]    = x[d]*cos(a_d) - x[d+64]*sin(a_d)
// out[d+64] = x[d+64]*cos(a_d) + x[d]*sin(a_d),  a_d = pos * 10000^(-d/64)
//
// One thread handles a float4 quad at d..d+3 plus the paired quad at d+64..d+67,
// for BOTH q and k (trig shared). 128 B of HBM traffic per thread; memory-bound.

constexpr int ROTARY_DIM = 128;
constexpr int HALF = 64;

__global__ __launch_bounds__(256) void rope_kernel(
    const int* __restrict__ positions,
    const float* __restrict__ q,
    const float* __restrict__ k,
    float* __restrict__ q_out,
    float* __restrict__ k_out,
    int n_threads)
{
    int tid = blockIdx.x * 256 + threadIdx.x;
    if (tid >= n_threads) return;

    const int j   = tid & 15;        // quad index within half-dim [0,16)
    const int row = tid >> 4;        // (b*S + s)*H + h
    const int bs  = row >> 5;        // H = 32 -> b*S + s
    const float pos = (float)positions[bs];

    const size_t base = (size_t)row * ROTARY_DIM + (size_t)(j << 2);

    const float4 q1 = *(const float4*)(q + base);
    const float4 q2 = *(const float4*)(q + base + HALF);
    const float4 k1 = *(const float4*)(k + base);
    const float4 k2 = *(const float4*)(k + base + HALF);

    // angle l: jj = 4*j + l, inv_freq = 2^(-jj * log2(10000)/64)
    const float C = 0.20762050593046014f;  // log2(10000)/64 (double-rounded)
    float s[4], c[4];
#pragma unroll
    for (int l = 0; l < 4; ++l) {
        float jj = (float)((j << 2) + l);
        float inv_freq = exp2f(-jj * C);
        float angle = pos * inv_freq;
        __sincosf(angle, &s[l], &c[l]);
    }

    const float* q1f = (const float*)&q1;
    const float* q2f = (const float*)&q2;
    const float* k1f = (const float*)&k1;
    const float* k2f = (const float*)&k2;
    float4 qo1, qo2, ko1, ko2;
    float* qo1f = (float*)&qo1;
    float* qo2f = (float*)&qo2;
    float* ko1f = (float*)&ko1;
    float* ko2f = (float*)&ko2;
#pragma unroll
    for (int l = 0; l < 4; ++l) {
        qo1f[l] = q1f[l] * c[l] - q2f[l] * s[l];
        qo2f[l] = q2f[l] * c[l] + q1f[l] * s[l];
        ko1f[l] = k1f[l] * c[l] - k2f[l] * s[l];
        ko2f[l] = k2f[l] * c[l] + k1f[l] * s[l];
    }

    *(float4*)(q_out + base)        = qo1;
    *(float4*)(q_out + base + HALF) = qo2;
    *(float4*)(k_out + base)        = ko1;
    *(float4*)(k_out + base + HALF) = ko2;
}

extern "C" void kernel_launch(void* const* d_in, const int* in_sizes, int n_in,
                              void* d_out, int out_size, void* d_ws, size_t ws_size,
                              hipStream_t stream) {
    const int*   positions = (const int*)d_in[0];
    const float* q         = (const float*)d_in[1];
    const float* k         = (const float*)d_in[2];
    float* q_out = (float*)d_out;
    const int n_q = in_sizes[1];          // B*S*E = 67,108,864
    float* k_out = q_out + (size_t)n_q;

    const int n_threads = n_q / 8;        // each thread covers 8 q (and 8 k) elements
    const int blocks = (n_threads + 255) / 256;
    rope_kernel<<<blocks, 256, 0, stream>>>(positions, q, k, q_out, k_out, n_threads);
}